// Round 9
// baseline (520.986 us; speedup 1.0000x reference)
//
#include <hip/hip_runtime.h>
#include <hip/hip_bf16.h>

#define DIVUP(a, b) (((a) + (b) - 1) / (b))

typedef __attribute__((ext_vector_type(8))) short bf16x8;
typedef __attribute__((ext_vector_type(4))) float f32x4;

// ---------- helpers ----------
__device__ __forceinline__ float bf2f(unsigned short u) {
    union { unsigned int i; float f; } v;
    v.i = ((unsigned int)u) << 16;
    return v.f;
}
__device__ __forceinline__ unsigned short f2bfu(float x) {
    return __hip_bfloat16_raw(__float2bfloat16(x)).x;   // RNE
}
__device__ __forceinline__ float gload(const void* p, int i, int isbf) {
    return isbf ? bf2f(((const unsigned short*)p)[i]) : ((const float*)p)[i];
}

// ---------- dtype detection (round-1 note; f32 vs bf16 inputs) ----------
__global__ void __launch_bounds__(256) detect_dtype(const void* __restrict__ feat,
                                                    int* __restrict__ flag) {
    __shared__ int cnt;
    if (threadIdx.x == 0) cnt = 0;
    __syncthreads();
    const unsigned short* u = (const unsigned short*)feat;
    int c = 0;
#pragma unroll
    for (int rep = 0; rep < 4; ++rep) {
        const int idx = threadIdx.x * 2 + rep * 512;
        const float v = fabsf(bf2f(u[idx]));
        c += (v > 1e-4f && v < 10.0f) ? 1 : 0;
    }
    atomicAdd(&cnt, c);
    __syncthreads();
    if (threadIdx.x == 0) *flag = (cnt > 512) ? 1 : 0;
}

// ================= CSR build: counting sort, zero global atomics =================
// bucket = col >> 7 (128 cols). EPB = 4096 edges/block -> B = 782 blocks
// (~3 blocks/CU; round-8: EPB=8192 gave 1.5 blocks/CU -> 11.6% occupancy, 55us).

__global__ void __launch_bounds__(256) parta_hist(const int* __restrict__ col,
                                                  int* __restrict__ cntRB,
                                                  int E, int B, int NB) {
    __shared__ int h[1024];
    for (int i = threadIdx.x; i < NB; i += 256) h[i] = 0;
    __syncthreads();
    const int base = blockIdx.x * 4096;
#pragma unroll
    for (int k = 0; k < 16; ++k) {
        const int e = base + k * 256 + threadIdx.x;
        if (e < E) atomicAdd(&h[__builtin_nontemporal_load(col + e) >> 7], 1);
    }
    __syncthreads();
    for (int i = threadIdx.x; i < NB; i += 256) cntRB[i * B + blockIdx.x] = h[i];
}

// ---------- 3-phase exclusive scan (n <= 1024*1024) ----------
__global__ void __launch_bounds__(256) scan_block_sums(const int* __restrict__ cnt,
                                                       int* __restrict__ bsum, int n) {
    __shared__ int red[256];
    const int base = blockIdx.x * 1024;
    int s = 0;
    for (int i = threadIdx.x; i < 1024; i += 256) {
        const int idx = base + i;
        s += (idx < n) ? cnt[idx] : 0;
    }
    red[threadIdx.x] = s;
    __syncthreads();
    for (int off = 128; off > 0; off >>= 1) {
        if (threadIdx.x < off) red[threadIdx.x] += red[threadIdx.x + off];
        __syncthreads();
    }
    if (threadIdx.x == 0) bsum[blockIdx.x] = red[0];
}

// capacity 1024 (4 per thread): exclusive scan in-place
__global__ void __launch_bounds__(256) scan_bsum(int* __restrict__ bsum, int nb) {
    __shared__ int tsum[256];
    const int x = threadIdx.x;
    int v[4];
    int s = 0;
#pragma unroll
    for (int k = 0; k < 4; ++k) {
        const int idx = x * 4 + k;
        v[k] = (idx < nb) ? bsum[idx] : 0;
        s += v[k];
    }
    tsum[x] = s;
    __syncthreads();
    int val = s;
    for (int off = 1; off < 256; off <<= 1) {
        const int t = (x >= off) ? tsum[x - off] : 0;
        __syncthreads();
        val += t;
        tsum[x] = val;
        __syncthreads();
    }
    int prefix = val - s;
#pragma unroll
    for (int k = 0; k < 4; ++k) {
        const int idx = x * 4 + k;
        if (idx < nb) bsum[idx] = prefix;
        prefix += v[k];
    }
}

__global__ void __launch_bounds__(256) scan_final(const int* __restrict__ cnt,
                                                  const int* __restrict__ bsum,
                                                  int* __restrict__ outp, int n) {
    __shared__ int tsum[256];
    const int base = blockIdx.x * 1024;
    const int x = threadIdx.x;
    int v[4];
    int s = 0;
#pragma unroll
    for (int k = 0; k < 4; ++k) {
        const int idx = base + x * 4 + k;
        v[k] = (idx < n) ? cnt[idx] : 0;
        s += v[k];
    }
    tsum[x] = s;
    __syncthreads();
    int val = s;
    for (int off = 1; off < 256; off <<= 1) {
        const int t = (x >= off) ? tsum[x - off] : 0;
        __syncthreads();
        val += t;
        tsum[x] = val;
        __syncthreads();
    }
    int prefix = bsum[blockIdx.x] + (val - s);
#pragma unroll
    for (int k = 0; k < 4; ++k) {
        const int idx = base + x * 4 + k;
        if (idx < n) outp[idx] = prefix;
        prefix += v[k];
    }
}

// ---------- tiled transpose: segoffT[block][bucket] <- segoff[bucket][block] ----------
// gives parta_scatter coalesced cursor loads (stride-B reads were 64B-line amplified)
__global__ void __launch_bounds__(256) transpose_seg(const int* __restrict__ in,
                                                     int* __restrict__ out,
                                                     int rows /*NB*/, int cols /*B*/) {
    __shared__ int t[32][33];
    const int bx = blockIdx.x * 32;   // col base (block index dim)
    const int by = blockIdx.y * 32;   // row base (bucket dim)
    const int tx = threadIdx.x & 31;
    const int ty = threadIdx.x >> 5;  // 0..7
#pragma unroll
    for (int dy = 0; dy < 32; dy += 8) {
        const int r = by + ty + dy, c = bx + tx;
        if (r < rows && c < cols) t[ty + dy][tx] = in[(size_t)r * cols + c];
    }
    __syncthreads();
#pragma unroll
    for (int dy = 0; dy < 32; dy += 8) {
        const int r = bx + ty + dy, c = by + tx;
        if (r < cols && c < rows) out[(size_t)r * rows + c] = t[tx][ty + dy];
    }
}

// ---------- phase A scatter: partition pairs into bucket segments ----------
__global__ void __launch_bounds__(256) parta_scatter(const int* __restrict__ row,
                                                     const int* __restrict__ col,
                                                     const int* __restrict__ segoffT,
                                                     int2* __restrict__ part,
                                                     int E, int B, int NB) {
    __shared__ int cur[1024];
    for (int i = threadIdx.x; i < NB; i += 256)
        cur[i] = segoffT[(size_t)blockIdx.x * NB + i];
    __syncthreads();
    const int base = blockIdx.x * 4096;
#pragma unroll
    for (int k = 0; k < 16; ++k) {
        const int e = base + k * 256 + threadIdx.x;
        if (e < E) {
            const int c = __builtin_nontemporal_load(col + e);
            const int r = __builtin_nontemporal_load(row + e);
            const int p = atomicAdd(&cur[c >> 7], 1);
            part[p] = make_int2(c, r);
        }
    }
}

// ---------- phase B: per-128-col-range CSR build + degrees + dinv ----------
__global__ void __launch_bounds__(256) csr_build(const int2* __restrict__ part,
                                                 const int* __restrict__ seg_off,
                                                 int* __restrict__ rowptr,
                                                 int* __restrict__ cnt,
                                                 float* __restrict__ dinv,
                                                 int* __restrict__ csr,
                                                 int E, int B, int NB, int N) {
    __shared__ int cl[128];
    __shared__ int sc[256];
    const int r  = blockIdx.x;
    const int c0 = r << 7;
    const int s0 = seg_off[r * B];
    const int s1 = (r == NB - 1) ? E : seg_off[(r + 1) * B];
    const int x = threadIdx.x;
    if (x < 128) cl[x] = 0;
    __syncthreads();
    for (int i = s0 + x; i < s1; i += 256)
        atomicAdd(&cl[part[i].x - c0], 1);
    __syncthreads();
    const int v = (x < 128) ? cl[x] : 0;
    sc[x] = v;
    __syncthreads();
    int val = v;
    for (int off = 1; off < 256; off <<= 1) {
        const int t = (x >= off) ? sc[x - off] : 0;
        __syncthreads();
        val += t;
        sc[x] = val;
        __syncthreads();
    }
    const int excl = val - v;
    const int c = c0 + x;
    if (x < 128 && c < N) {
        rowptr[c] = s0 + excl;
        cnt[c]    = v;
        dinv[c]   = rsqrtf((float)v + 1.0f);
    }
    if (x < 128) cl[x] = s0 + excl;   // reuse as cursor
    __syncthreads();
    for (int i = s0 + x; i < s1; i += 256) {
        const int2 pr = part[i];
        const int p = atomicAdd(&cl[pr.x - c0], 1);
        csr[p] = pr.y << 7;           // row*128: byte offset template, shifted per layer
    }
}

// ================= MFMA GEMM: y = bf16((x @ W) * dinv[node]) =================
// A[m=lane&15][k=quad*8+j] from global; B via ds_read from Wt[n][k]; D col=lane&15,row=quad*4+reg
template<int F_IN, int F_OUT, int XMODE, int SPLIT>
__global__ void __launch_bounds__(256) gemm_mfma(const void* __restrict__ x,
                                                 const void* __restrict__ W,
                                                 const float* __restrict__ dinv,
                                                 unsigned short* __restrict__ ylo,
                                                 unsigned short* __restrict__ yhi,
                                                 int n, const int* __restrict__ flag) {
    constexpr int KS = F_IN / 32;
    constexpr int NT = F_OUT / 16;
    constexpr int WPAD = F_IN + 8;
    const int isbf = *flag;
    __shared__ unsigned short Wt[F_OUT * WPAD];

    for (int i = threadIdx.x; i < F_IN * F_OUT; i += 256) {
        const int k = i / F_OUT, nn = i % F_OUT;
        Wt[nn * WPAD + k] = f2bfu(gload(W, i, isbf));
    }
    __syncthreads();

    const int lane = threadIdx.x & 63;
    const int wid  = threadIdx.x >> 6;
    const int m    = lane & 15;
    const int quad = lane >> 4;
    const int nodeA = blockIdx.x * 64 + wid * 16 + m;

    bf16x8 afr[KS];
    if (nodeA < n) {
        if (XMODE == 1 || isbf) {
            const unsigned short* xr = (const unsigned short*)x + (size_t)nodeA * F_IN;
#pragma unroll
            for (int s = 0; s < KS; ++s)
                afr[s] = *(const bf16x8*)(xr + s * 32 + quad * 8);
        } else {
            const float* xr = (const float*)x + (size_t)nodeA * F_IN;
#pragma unroll
            for (int s = 0; s < KS; ++s) {
                const float4 v0 = *(const float4*)(xr + s * 32 + quad * 8);
                const float4 v1 = *(const float4*)(xr + s * 32 + quad * 8 + 4);
                bf16x8 a;
                a[0] = (short)f2bfu(v0.x); a[1] = (short)f2bfu(v0.y);
                a[2] = (short)f2bfu(v0.z); a[3] = (short)f2bfu(v0.w);
                a[4] = (short)f2bfu(v1.x); a[5] = (short)f2bfu(v1.y);
                a[6] = (short)f2bfu(v1.z); a[7] = (short)f2bfu(v1.w);
                afr[s] = a;
            }
        }
    } else {
#pragma unroll
        for (int s = 0; s < KS; ++s) afr[s] = (bf16x8)(short)0;
    }

    f32x4 acc[NT];
#pragma unroll
    for (int t = 0; t < NT; ++t) acc[t] = (f32x4)0.f;

#pragma unroll
    for (int t = 0; t < NT; ++t) {
#pragma unroll
        for (int s = 0; s < KS; ++s) {
            const bf16x8 bfr = *(const bf16x8*)(Wt + (t * 16 + m) * WPAD + s * 32 + quad * 8);
            acc[t] = __builtin_amdgcn_mfma_f32_16x16x32_bf16(afr[s], bfr, acc[t], 0, 0, 0);
        }
    }

#pragma unroll
    for (int r = 0; r < 4; ++r) {
        const int ng = blockIdx.x * 64 + wid * 16 + quad * 4 + r;
        if (ng < n) {
            const float scl = dinv[ng];
#pragma unroll
            for (int t = 0; t < NT; ++t) {
                const int f = t * 16 + m;
                const unsigned short v = f2bfu(acc[t][r] * scl);
                if (SPLIT) {
                    if (t < NT / 2) ylo[(size_t)ng * (F_OUT / 2) + f] = v;
                    else            yhi[(size_t)ng * (F_OUT / 2) + f - F_OUT / 2] = v;
                } else {
                    ylo[(size_t)ng * F_OUT + f] = v;
                }
            }
        }
    }
}

// ---------- aggregate + fused epilogue (16-deep MLP; nt on streaming csr/out) ----------
template<int F, int SH>
__global__ void __launch_bounds__(256) aggregate(const unsigned short* __restrict__ y,
                                                 const int* __restrict__ csr,
                                                 const int* __restrict__ rowptr,
                                                 const int* __restrict__ cnt,
                                                 const float* __restrict__ dinv,
                                                 const void* __restrict__ b,
                                                 unsigned short* __restrict__ out,
                                                 int n, int OSTR, int fofs,
                                                 const int* __restrict__ flag) {
    const int isbf = *flag;
    constexpr int GP = 64 / F;
    const int lane = threadIdx.x & 63;
    const int sub  = lane / F;
    const int f    = lane % F;
    const int wave = (blockIdx.x * 256 + threadIdx.x) >> 6;
    const int node = wave * GP + sub;
    if (node >= n) return;

    const int beg = rowptr[node];
    const int deg = cnt[node];
    const char* yb = (const char*)y;
    const int f2b = f * 2;
    float acc = 0.f;
    int j = 0;
    for (; j + 16 <= deg; j += 16) {
        int o[16];
#pragma unroll
        for (int k = 0; k < 16; ++k)
            o[k] = __builtin_nontemporal_load(csr + beg + j + k) >> SH;
        float v[16];
#pragma unroll
        for (int k = 0; k < 16; ++k)
            v[k] = bf2f(*(const unsigned short*)(yb + o[k] + f2b));
        const float s0 = ((v[0] + v[1]) + (v[2] + v[3])) + ((v[4] + v[5]) + (v[6] + v[7]));
        const float s1 = ((v[8] + v[9]) + (v[10] + v[11])) + ((v[12] + v[13]) + (v[14] + v[15]));
        acc += s0 + s1;
    }
    for (; j + 4 <= deg; j += 4) {
        int o[4];
#pragma unroll
        for (int k = 0; k < 4; ++k)
            o[k] = __builtin_nontemporal_load(csr + beg + j + k) >> SH;
        float v[4];
#pragma unroll
        for (int k = 0; k < 4; ++k)
            v[k] = bf2f(*(const unsigned short*)(yb + o[k] + f2b));
        acc += (v[0] + v[1]) + (v[2] + v[3]);
    }
    for (; j < deg; ++j)
        acc += bf2f(*(const unsigned short*)(yb + (__builtin_nontemporal_load(csr + beg + j) >> SH) + f2b));

    const float self = bf2f(y[(size_t)node * F + f]);
    const float v = dinv[node] * (acc + self) + gload(b, fofs + f, isbf);
    const unsigned short res = f2bfu(fmaxf(v, 0.f));
    __builtin_nontemporal_store(res, out + (size_t)node * OSTR + fofs + f);
}

// ---------- dense head: out = relu(concat(f1,f2,f3) @ Wfc + bfc) ----------
__global__ void __launch_bounds__(256) head_kernel(const unsigned short* __restrict__ f1,
                                                   const unsigned short* __restrict__ f2,
                                                   const unsigned short* __restrict__ f3,
                                                   const void* __restrict__ Wfc,
                                                   const void* __restrict__ bfc,
                                                   void* __restrict__ out, int n,
                                                   const int* __restrict__ flag) {
    const int isbf = *flag;
    __shared__ float Ws[112 * 16];
    for (int i = threadIdx.x; i < 112 * 16; i += 256) Ws[i] = gload(Wfc, i, isbf);
    __syncthreads();

    const int h    = threadIdx.x & 3;
    const int node = blockIdx.x * 64 + (threadIdx.x >> 2);
    if (node >= n) return;

    float4 acc = make_float4(gload(bfc, 4 * h + 0, isbf), gload(bfc, 4 * h + 1, isbf),
                             gload(bfc, 4 * h + 2, isbf), gload(bfc, 4 * h + 3, isbf));

    const unsigned short* x1 = f1 + (size_t)node * 64;
#pragma unroll
    for (int k4 = 0; k4 < 16; ++k4) {
        const ushort4 xu = *(const ushort4*)(x1 + 4 * k4);
        const float xa[4] = {bf2f(xu.x), bf2f(xu.y), bf2f(xu.z), bf2f(xu.w)};
#pragma unroll
        for (int j = 0; j < 4; ++j) {
            const float4 wv = *(const float4*)(Ws + (4 * k4 + j) * 16 + 4 * h);
            acc.x = fmaf(xa[j], wv.x, acc.x); acc.y = fmaf(xa[j], wv.y, acc.y);
            acc.z = fmaf(xa[j], wv.z, acc.z); acc.w = fmaf(xa[j], wv.w, acc.w);
        }
    }
    const unsigned short* x2 = f2 + (size_t)node * 32;
#pragma unroll
    for (int k4 = 0; k4 < 8; ++k4) {
        const ushort4 xu = *(const ushort4*)(x2 + 4 * k4);
        const float xa[4] = {bf2f(xu.x), bf2f(xu.y), bf2f(xu.z), bf2f(xu.w)};
#pragma unroll
        for (int j = 0; j < 4; ++j) {
            const float4 wv = *(const float4*)(Ws + (64 + 4 * k4 + j) * 16 + 4 * h);
            acc.x = fmaf(xa[j], wv.x, acc.x); acc.y = fmaf(xa[j], wv.y, acc.y);
            acc.z = fmaf(xa[j], wv.z, acc.z); acc.w = fmaf(xa[j], wv.w, acc.w);
        }
    }
    const unsigned short* x3 = f3 + (size_t)node * 16;
#pragma unroll
    for (int k4 = 0; k4 < 4; ++k4) {
        const ushort4 xu = *(const ushort4*)(x3 + 4 * k4);
        const float xa[4] = {bf2f(xu.x), bf2f(xu.y), bf2f(xu.z), bf2f(xu.w)};
#pragma unroll
        for (int j = 0; j < 4; ++j) {
            const float4 wv = *(const float4*)(Ws + (96 + 4 * k4 + j) * 16 + 4 * h);
            acc.x = fmaf(xa[j], wv.x, acc.x); acc.y = fmaf(xa[j], wv.y, acc.y);
            acc.z = fmaf(xa[j], wv.z, acc.z); acc.w = fmaf(xa[j], wv.w, acc.w);
        }
    }

    const float4 r = make_float4(fmaxf(acc.x, 0.f), fmaxf(acc.y, 0.f),
                                 fmaxf(acc.z, 0.f), fmaxf(acc.w, 0.f));
    const size_t o = (size_t)node * 16 + 4 * h;
    if (isbf) {
        ushort4 u;
        u.x = f2bfu(r.x); u.y = f2bfu(r.y); u.z = f2bfu(r.z); u.w = f2bfu(r.w);
        *(ushort4*)((unsigned short*)out + o) = u;
    } else {
        *(float4*)((float*)out + o) = r;
    }
}

// ---------- launch ----------
extern "C" void kernel_launch(void* const* d_in, const int* in_sizes, int n_in,
                              void* d_out, int out_size, void* d_ws, size_t ws_size,
                              hipStream_t stream) {
    const int*  edges = (const int*)d_in[0];
    const void* feat  = d_in[1];
    const void* W1    = d_in[2];
    const void* b1    = d_in[3];
    const void* W2    = d_in[4];
    const void* b2    = d_in[5];
    const void* W3    = d_in[6];
    const void* b3    = d_in[7];
    const void* Wfc   = d_in[8];
    const void* bfc   = d_in[9];

    const int E = in_sizes[0] / 2;
    const int N = in_sizes[1] / 128;
    const int* row = edges;
    const int* col = edges + E;

    const int B  = DIVUP(E, 4096);     // phase-A blocks
    const int NB = DIVUP(N, 128);      // 128-col buckets / phase-B blocks
    const int NBB = NB * B;            // scan length (<= 1M)

    char* p = (char*)d_ws;
    int*   flag    = (int*)p;               p += 16;
    float* dinv    = (float*)p;             p += (size_t)N * 4;
    int*   cnt     = (int*)p;               p += (size_t)N * 4;
    int*   rowptr  = (int*)p;               p += (size_t)N * 4;
    int*   csr     = (int*)p;               p += (size_t)E * 4;
    int2*  part    = (int2*)p;              p += (size_t)E * 8;
    unsigned short* ylo = (unsigned short*)p; p += (size_t)N * 32 * 2;
    unsigned short* yhi = (unsigned short*)p; p += (size_t)N * 32 * 2;
    unsigned short* f1 = (unsigned short*)p; p += (size_t)N * 64 * 2;
    unsigned short* f2 = (unsigned short*)p; p += (size_t)N * 32 * 2;
    unsigned short* f3 = (unsigned short*)p; p += (size_t)N * 16 * 2;
    int*   cntRB   = (int*)p;               p += (size_t)NBB * 4;
    int*   segoff  = (int*)p;               p += (size_t)NBB * 4;
    int*   segoffT = (int*)p;               p += (size_t)NBB * 4;
    int*   bsum    = (int*)p;

    detect_dtype<<<1, 256, 0, stream>>>(feat, flag);

    // CSR build (also produces cnt, rowptr, dinv) — no global atomics
    parta_hist<<<B, 256, 0, stream>>>(col, cntRB, E, B, NB);
    const int nb = DIVUP(NBB, 1024);
    scan_block_sums<<<nb, 256, 0, stream>>>(cntRB, bsum, NBB);
    scan_bsum<<<1, 256, 0, stream>>>(bsum, nb);
    scan_final<<<nb, 256, 0, stream>>>(cntRB, bsum, segoff, NBB);
    {
        dim3 g(DIVUP(B, 32), DIVUP(NB, 32));
        transpose_seg<<<g, 256, 0, stream>>>(segoff, segoffT, NB, B);
    }
    parta_scatter<<<B, 256, 0, stream>>>(row, col, segoffT, part, E, B, NB);
    csr_build<<<NB, 256, 0, stream>>>(part, segoff, rowptr, cnt, dinv, csr, E, B, NB, N);

    // layer 1: 128 -> 64 (split halves); aggregate one half per pass
    gemm_mfma<128, 64, 0, 1><<<DIVUP(N, 64), 256, 0, stream>>>(feat, W1, dinv, ylo, yhi, N, flag);
    aggregate<32, 1><<<DIVUP(N, 8), 256, 0, stream>>>(ylo, csr, rowptr, cnt, dinv, b1, f1, N, 64, 0, flag);
    aggregate<32, 1><<<DIVUP(N, 8), 256, 0, stream>>>(yhi, csr, rowptr, cnt, dinv, b1, f1, N, 64, 32, flag);

    // layer 2: 64 -> 32 (y reuses ylo region)
    gemm_mfma<64, 32, 1, 0><<<DIVUP(N, 64), 256, 0, stream>>>(f1, W2, dinv, ylo, ylo, N, flag);
    aggregate<32, 1><<<DIVUP(N, 8), 256, 0, stream>>>(ylo, csr, rowptr, cnt, dinv, b2, f2, N, 32, 0, flag);

    // layer 3: 32 -> 16
    gemm_mfma<32, 16, 1, 0><<<DIVUP(N, 64), 256, 0, stream>>>(f2, W3, dinv, ylo, ylo, N, flag);
    aggregate<16, 2><<<DIVUP(N, 16), 256, 0, stream>>>(ylo, csr, rowptr, cnt, dinv, b3, f3, N, 16, 0, flag);

    // dense head
    head_kernel<<<DIVUP(N, 64), 256, 0, stream>>>(f1, f2, f3, Wfc, bfc, d_out, N, flag);
}

// Round 10
// 468.569 us; speedup vs baseline: 1.1119x; 1.1119x over previous
//
#include <hip/hip_runtime.h>
#include <hip/hip_bf16.h>

#define DIVUP(a, b) (((a) + (b) - 1) / (b))

typedef __attribute__((ext_vector_type(8))) short bf16x8;
typedef __attribute__((ext_vector_type(4))) float f32x4;

// ---------- helpers ----------
__device__ __forceinline__ float bf2f(unsigned short u) {
    union { unsigned int i; float f; } v;
    v.i = ((unsigned int)u) << 16;
    return v.f;
}
__device__ __forceinline__ unsigned short f2bfu(float x) {
    return __hip_bfloat16_raw(__float2bfloat16(x)).x;   // RNE
}
__device__ __forceinline__ float gload(const void* p, int i, int isbf) {
    return isbf ? bf2f(((const unsigned short*)p)[i]) : ((const float*)p)[i];
}

// ---------- dtype detection (round-1 note; f32 vs bf16 inputs) ----------
__global__ void __launch_bounds__(256) detect_dtype(const void* __restrict__ feat,
                                                    int* __restrict__ flag) {
    __shared__ int cnt;
    if (threadIdx.x == 0) cnt = 0;
    __syncthreads();
    const unsigned short* u = (const unsigned short*)feat;
    int c = 0;
#pragma unroll
    for (int rep = 0; rep < 4; ++rep) {
        const int idx = threadIdx.x * 2 + rep * 512;
        const float v = fabsf(bf2f(u[idx]));
        c += (v > 1e-4f && v < 10.0f) ? 1 : 0;
    }
    atomicAdd(&cnt, c);
    __syncthreads();
    if (threadIdx.x == 0) *flag = (cnt > 512) ? 1 : 0;
}

// ================= CSR build: counting sort, zero global atomics =================
// bucket = col >> 8 (256 cols), EPB = 8192 (round-9 lesson: finer buckets cut
// scatter run length below a 64B line -> write amplification 90MB; 256-col
// buckets give ~21-entry runs). part entry packed to 4B: (row<<8)|(col&255).

__global__ void __launch_bounds__(256) parta_hist(const int* __restrict__ col,
                                                  int* __restrict__ cntRB,
                                                  int E, int B, int NB) {
    __shared__ int h[512];
    for (int i = threadIdx.x; i < NB; i += 256) h[i] = 0;
    __syncthreads();
    const int base = blockIdx.x * 8192;
#pragma unroll
    for (int k = 0; k < 32; ++k) {
        const int e = base + k * 256 + threadIdx.x;
        if (e < E) atomicAdd(&h[__builtin_nontemporal_load(col + e) >> 8], 1);
    }
    __syncthreads();
    for (int i = threadIdx.x; i < NB; i += 256) cntRB[i * B + blockIdx.x] = h[i];
}

// ---------- 3-phase exclusive scan (n <= 1024*1024) ----------
__global__ void __launch_bounds__(256) scan_block_sums(const int* __restrict__ cnt,
                                                       int* __restrict__ bsum, int n) {
    __shared__ int red[256];
    const int base = blockIdx.x * 1024;
    int s = 0;
    for (int i = threadIdx.x; i < 1024; i += 256) {
        const int idx = base + i;
        s += (idx < n) ? cnt[idx] : 0;
    }
    red[threadIdx.x] = s;
    __syncthreads();
    for (int off = 128; off > 0; off >>= 1) {
        if (threadIdx.x < off) red[threadIdx.x] += red[threadIdx.x + off];
        __syncthreads();
    }
    if (threadIdx.x == 0) bsum[blockIdx.x] = red[0];
}

__global__ void __launch_bounds__(256) scan_bsum(int* __restrict__ bsum, int nb) {
    __shared__ int tsum[256];
    const int x = threadIdx.x;
    int v[4];
    int s = 0;
#pragma unroll
    for (int k = 0; k < 4; ++k) {
        const int idx = x * 4 + k;
        v[k] = (idx < nb) ? bsum[idx] : 0;
        s += v[k];
    }
    tsum[x] = s;
    __syncthreads();
    int val = s;
    for (int off = 1; off < 256; off <<= 1) {
        const int t = (x >= off) ? tsum[x - off] : 0;
        __syncthreads();
        val += t;
        tsum[x] = val;
        __syncthreads();
    }
    int prefix = val - s;
#pragma unroll
    for (int k = 0; k < 4; ++k) {
        const int idx = x * 4 + k;
        if (idx < nb) bsum[idx] = prefix;
        prefix += v[k];
    }
}

__global__ void __launch_bounds__(256) scan_final(const int* __restrict__ cnt,
                                                  const int* __restrict__ bsum,
                                                  int* __restrict__ outp, int n) {
    __shared__ int tsum[256];
    const int base = blockIdx.x * 1024;
    const int x = threadIdx.x;
    int v[4];
    int s = 0;
#pragma unroll
    for (int k = 0; k < 4; ++k) {
        const int idx = base + x * 4 + k;
        v[k] = (idx < n) ? cnt[idx] : 0;
        s += v[k];
    }
    tsum[x] = s;
    __syncthreads();
    int val = s;
    for (int off = 1; off < 256; off <<= 1) {
        const int t = (x >= off) ? tsum[x - off] : 0;
        __syncthreads();
        val += t;
        tsum[x] = val;
        __syncthreads();
    }
    int prefix = bsum[blockIdx.x] + (val - s);
#pragma unroll
    for (int k = 0; k < 4; ++k) {
        const int idx = base + x * 4 + k;
        if (idx < n) outp[idx] = prefix;
        prefix += v[k];
    }
}

// ---------- tiled transpose: segoffT[block][bucket] <- segoff[bucket][block] ----------
__global__ void __launch_bounds__(256) transpose_seg(const int* __restrict__ in,
                                                     int* __restrict__ out,
                                                     int rows /*NB*/, int cols /*B*/) {
    __shared__ int t[32][33];
    const int bx = blockIdx.x * 32;
    const int by = blockIdx.y * 32;
    const int tx = threadIdx.x & 31;
    const int ty = threadIdx.x >> 5;
#pragma unroll
    for (int dy = 0; dy < 32; dy += 8) {
        const int r = by + ty + dy, c = bx + tx;
        if (r < rows && c < cols) t[ty + dy][tx] = in[(size_t)r * cols + c];
    }
    __syncthreads();
#pragma unroll
    for (int dy = 0; dy < 32; dy += 8) {
        const int r = bx + ty + dy, c = by + tx;
        if (r < cols && c < rows) out[(size_t)r * rows + c] = t[tx][ty + dy];
    }
}

// ---------- phase A scatter: packed pairs into bucket segments ----------
__global__ void __launch_bounds__(256) parta_scatter(const int* __restrict__ row,
                                                     const int* __restrict__ col,
                                                     const int* __restrict__ segoffT,
                                                     int* __restrict__ part,
                                                     int E, int B, int NB) {
    __shared__ int cur[512];
    for (int i = threadIdx.x; i < NB; i += 256)
        cur[i] = segoffT[(size_t)blockIdx.x * NB + i];
    __syncthreads();
    const int base = blockIdx.x * 8192;
#pragma unroll
    for (int k = 0; k < 32; ++k) {
        const int e = base + k * 256 + threadIdx.x;
        if (e < E) {
            const int c = __builtin_nontemporal_load(col + e);
            const int r = __builtin_nontemporal_load(row + e);
            const int p = atomicAdd(&cur[c >> 8], 1);
            part[p] = (r << 8) | (c & 255);   // 4B packed (row<2^17)
        }
    }
}

// ---------- phase B: per-256-col-range CSR build + degrees + dinv ----------
__global__ void __launch_bounds__(256) csr_build(const int* __restrict__ part,
                                                 const int* __restrict__ seg_off,
                                                 int* __restrict__ rowptr,
                                                 int* __restrict__ cnt,
                                                 float* __restrict__ dinv,
                                                 int* __restrict__ csr,
                                                 int E, int B, int NB, int N) {
    __shared__ int cl[256];
    __shared__ int sc[256];
    const int r  = blockIdx.x;
    const int c0 = r << 8;
    const int s0 = seg_off[r * B];
    const int s1 = (r == NB - 1) ? E : seg_off[(r + 1) * B];
    const int x = threadIdx.x;
    cl[x] = 0;
    __syncthreads();
    for (int i = s0 + x; i < s1; i += 256)
        atomicAdd(&cl[part[i] & 255], 1);
    __syncthreads();
    const int v = cl[x];
    sc[x] = v;
    __syncthreads();
    int val = v;
    for (int off = 1; off < 256; off <<= 1) {
        const int t = (x >= off) ? sc[x - off] : 0;
        __syncthreads();
        val += t;
        sc[x] = val;
        __syncthreads();
    }
    const int excl = val - v;
    const int c = c0 + x;
    if (c < N) {
        rowptr[c] = s0 + excl;
        cnt[c]    = v;
        dinv[c]   = rsqrtf((float)v + 1.0f);
    }
    cl[x] = s0 + excl;   // reuse as cursor
    __syncthreads();
    for (int i = s0 + x; i < s1; i += 256) {
        const int e = part[i];
        const int p = atomicAdd(&cl[e & 255], 1);
        csr[p] = (e >> 8) << 7;   // row*128: byte-offset template (>>2 for 32B tile rows)
    }
}

// ================= MFMA GEMM: tile-major y[t][node][16] = bf16((x@W)*dinv) =================
// A[m=lane&15][k=quad*8+j] from global; B via ds_read from Wt[n][k];
// D col=lane&15, row=quad*4+reg. Each 16-col output tile t goes to y + t*QS.
template<int F_IN, int F_OUT, int XMODE>
__global__ void __launch_bounds__(256) gemm_mfma(const void* __restrict__ x,
                                                 const void* __restrict__ W,
                                                 const float* __restrict__ dinv,
                                                 unsigned short* __restrict__ y,
                                                 size_t QS, int n,
                                                 const int* __restrict__ flag) {
    constexpr int KS = F_IN / 32;
    constexpr int NT = F_OUT / 16;
    constexpr int WPAD = F_IN + 8;
    const int isbf = *flag;
    __shared__ unsigned short Wt[F_OUT * WPAD];

    for (int i = threadIdx.x; i < F_IN * F_OUT; i += 256) {
        const int k = i / F_OUT, nn = i % F_OUT;
        Wt[nn * WPAD + k] = f2bfu(gload(W, i, isbf));
    }
    __syncthreads();

    const int lane = threadIdx.x & 63;
    const int wid  = threadIdx.x >> 6;
    const int m    = lane & 15;
    const int quad = lane >> 4;
    const int nodeA = blockIdx.x * 64 + wid * 16 + m;

    bf16x8 afr[KS];
    if (nodeA < n) {
        if (XMODE == 1 || isbf) {
            const unsigned short* xr = (const unsigned short*)x + (size_t)nodeA * F_IN;
#pragma unroll
            for (int s = 0; s < KS; ++s)
                afr[s] = *(const bf16x8*)(xr + s * 32 + quad * 8);
        } else {
            const float* xr = (const float*)x + (size_t)nodeA * F_IN;
#pragma unroll
            for (int s = 0; s < KS; ++s) {
                const float4 v0 = *(const float4*)(xr + s * 32 + quad * 8);
                const float4 v1 = *(const float4*)(xr + s * 32 + quad * 8 + 4);
                bf16x8 a;
                a[0] = (short)f2bfu(v0.x); a[1] = (short)f2bfu(v0.y);
                a[2] = (short)f2bfu(v0.z); a[3] = (short)f2bfu(v0.w);
                a[4] = (short)f2bfu(v1.x); a[5] = (short)f2bfu(v1.y);
                a[6] = (short)f2bfu(v1.z); a[7] = (short)f2bfu(v1.w);
                afr[s] = a;
            }
        }
    } else {
#pragma unroll
        for (int s = 0; s < KS; ++s) afr[s] = (bf16x8)(short)0;
    }

    f32x4 acc[NT];
#pragma unroll
    for (int t = 0; t < NT; ++t) acc[t] = (f32x4)0.f;

#pragma unroll
    for (int t = 0; t < NT; ++t) {
#pragma unroll
        for (int s = 0; s < KS; ++s) {
            const bf16x8 bfr = *(const bf16x8*)(Wt + (t * 16 + m) * WPAD + s * 32 + quad * 8);
            acc[t] = __builtin_amdgcn_mfma_f32_16x16x32_bf16(afr[s], bfr, acc[t], 0, 0, 0);
        }
    }

#pragma unroll
    for (int r = 0; r < 4; ++r) {
        const int ng = blockIdx.x * 64 + wid * 16 + quad * 4 + r;
        if (ng < n) {
            const float scl = dinv[ng];
#pragma unroll
            for (int t = 0; t < NT; ++t)
                y[(size_t)t * QS + (size_t)ng * 16 + m] = f2bfu(acc[t][r] * scl);
        }
    }
}

// ---------- aggregate one 16-col tile + fused epilogue ----------
// y points at tile base: y[node][16] (32B rows, 3.2MB working set -> L2-resident).
// out[node*OSTR + fofs + f] = bf16(relu(dinv*(sum + self) + b[fofs+f]))
// csr entry = row<<7 -> row*32B via >>2.
__global__ void __launch_bounds__(256) aggregate16(const unsigned short* __restrict__ y,
                                                   const int* __restrict__ csr,
                                                   const int* __restrict__ rowptr,
                                                   const int* __restrict__ cnt,
                                                   const float* __restrict__ dinv,
                                                   const void* __restrict__ b,
                                                   unsigned short* __restrict__ out,
                                                   int n, int OSTR, int fofs,
                                                   const int* __restrict__ flag) {
    const int isbf = *flag;
    const int lane = threadIdx.x & 63;
    const int sub  = lane >> 4;          // 4 nodes per wave
    const int f    = lane & 15;
    const int wave = (blockIdx.x * 256 + threadIdx.x) >> 6;
    const int node = wave * 4 + sub;
    if (node >= n) return;

    const int beg = rowptr[node];
    const int deg = cnt[node];
    const char* yb = (const char*)y;
    const int f2b = f * 2;
    float acc = 0.f;
    int j = 0;
    for (; j + 16 <= deg; j += 16) {
        int o[16];
#pragma unroll
        for (int k = 0; k < 16; ++k) o[k] = csr[beg + j + k] >> 2;
        float v[16];
#pragma unroll
        for (int k = 0; k < 16; ++k)
            v[k] = bf2f(*(const unsigned short*)(yb + o[k] + f2b));
        const float s0 = ((v[0] + v[1]) + (v[2] + v[3])) + ((v[4] + v[5]) + (v[6] + v[7]));
        const float s1 = ((v[8] + v[9]) + (v[10] + v[11])) + ((v[12] + v[13]) + (v[14] + v[15]));
        acc += s0 + s1;
    }
    for (; j + 4 <= deg; j += 4) {
        int o[4];
#pragma unroll
        for (int k = 0; k < 4; ++k) o[k] = csr[beg + j + k] >> 2;
        float v[4];
#pragma unroll
        for (int k = 0; k < 4; ++k)
            v[k] = bf2f(*(const unsigned short*)(yb + o[k] + f2b));
        acc += (v[0] + v[1]) + (v[2] + v[3]);
    }
    for (; j < deg; ++j)
        acc += bf2f(*(const unsigned short*)(yb + (csr[beg + j] >> 2) + f2b));

    const float self = bf2f(y[(size_t)node * 16 + f]);
    const float v = dinv[node] * (acc + self) + gload(b, fofs + f, isbf);
    out[(size_t)node * OSTR + fofs + f] = f2bfu(fmaxf(v, 0.f));
}

// ---------- dense head: out = relu(concat(f1,f2,f3) @ Wfc + bfc) ----------
__global__ void __launch_bounds__(256) head_kernel(const unsigned short* __restrict__ f1,
                                                   const unsigned short* __restrict__ f2,
                                                   const unsigned short* __restrict__ f3,
                                                   const void* __restrict__ Wfc,
                                                   const void* __restrict__ bfc,
                                                   void* __restrict__ out, int n,
                                                   const int* __restrict__ flag) {
    const int isbf = *flag;
    __shared__ float Ws[112 * 16];
    for (int i = threadIdx.x; i < 112 * 16; i += 256) Ws[i] = gload(Wfc, i, isbf);
    __syncthreads();

    const int h    = threadIdx.x & 3;
    const int node = blockIdx.x * 64 + (threadIdx.x >> 2);
    if (node >= n) return;

    float4 acc = make_float4(gload(bfc, 4 * h + 0, isbf), gload(bfc, 4 * h + 1, isbf),
                             gload(bfc, 4 * h + 2, isbf), gload(bfc, 4 * h + 3, isbf));

    const unsigned short* x1 = f1 + (size_t)node * 64;
#pragma unroll
    for (int k4 = 0; k4 < 16; ++k4) {
        const ushort4 xu = *(const ushort4*)(x1 + 4 * k4);
        const float xa[4] = {bf2f(xu.x), bf2f(xu.y), bf2f(xu.z), bf2f(xu.w)};
#pragma unroll
        for (int j = 0; j < 4; ++j) {
            const float4 wv = *(const float4*)(Ws + (4 * k4 + j) * 16 + 4 * h);
            acc.x = fmaf(xa[j], wv.x, acc.x); acc.y = fmaf(xa[j], wv.y, acc.y);
            acc.z = fmaf(xa[j], wv.z, acc.z); acc.w = fmaf(xa[j], wv.w, acc.w);
        }
    }
    const unsigned short* x2 = f2 + (size_t)node * 32;
#pragma unroll
    for (int k4 = 0; k4 < 8; ++k4) {
        const ushort4 xu = *(const ushort4*)(x2 + 4 * k4);
        const float xa[4] = {bf2f(xu.x), bf2f(xu.y), bf2f(xu.z), bf2f(xu.w)};
#pragma unroll
        for (int j = 0; j < 4; ++j) {
            const float4 wv = *(const float4*)(Ws + (64 + 4 * k4 + j) * 16 + 4 * h);
            acc.x = fmaf(xa[j], wv.x, acc.x); acc.y = fmaf(xa[j], wv.y, acc.y);
            acc.z = fmaf(xa[j], wv.z, acc.z); acc.w = fmaf(xa[j], wv.w, acc.w);
        }
    }
    const unsigned short* x3 = f3 + (size_t)node * 16;
#pragma unroll
    for (int k4 = 0; k4 < 4; ++k4) {
        const ushort4 xu = *(const ushort4*)(x3 + 4 * k4);
        const float xa[4] = {bf2f(xu.x), bf2f(xu.y), bf2f(xu.z), bf2f(xu.w)};
#pragma unroll
        for (int j = 0; j < 4; ++j) {
            const float4 wv = *(const float4*)(Ws + (96 + 4 * k4 + j) * 16 + 4 * h);
            acc.x = fmaf(xa[j], wv.x, acc.x); acc.y = fmaf(xa[j], wv.y, acc.y);
            acc.z = fmaf(xa[j], wv.z, acc.z); acc.w = fmaf(xa[j], wv.w, acc.w);
        }
    }

    const float4 r = make_float4(fmaxf(acc.x, 0.f), fmaxf(acc.y, 0.f),
                                 fmaxf(acc.z, 0.f), fmaxf(acc.w, 0.f));
    const size_t o = (size_t)node * 16 + 4 * h;
    if (isbf) {
        ushort4 u;
        u.x = f2bfu(r.x); u.y = f2bfu(r.y); u.z = f2bfu(r.z); u.w = f2bfu(r.w);
        *(ushort4*)((unsigned short*)out + o) = u;
    } else {
        *(float4*)((float*)out + o) = r;
    }
}

// ---------- launch ----------
extern "C" void kernel_launch(void* const* d_in, const int* in_sizes, int n_in,
                              void* d_out, int out_size, void* d_ws, size_t ws_size,
                              hipStream_t stream) {
    const int*  edges = (const int*)d_in[0];
    const void* feat  = d_in[1];
    const void* W1    = d_in[2];
    const void* b1    = d_in[3];
    const void* W2    = d_in[4];
    const void* b2    = d_in[5];
    const void* W3    = d_in[6];
    const void* b3    = d_in[7];
    const void* Wfc   = d_in[8];
    const void* bfc   = d_in[9];

    const int E = in_sizes[0] / 2;
    const int N = in_sizes[1] / 128;
    const int* row = edges;
    const int* col = edges + E;

    const int B  = DIVUP(E, 8192);     // phase-A blocks
    const int NB = DIVUP(N, 256);      // 256-col buckets / phase-B blocks
    const int NBB = NB * B;

    char* p = (char*)d_ws;
    int*   flag    = (int*)p;               p += 16;
    float* dinv    = (float*)p;             p += (size_t)N * 4;
    int*   cnt     = (int*)p;               p += (size_t)N * 4;
    int*   rowptr  = (int*)p;               p += (size_t)N * 4;
    int*   csr     = (int*)p;               p += (size_t)E * 4;
    int*   part    = (int*)p;               p += (size_t)E * 4;   // packed 4B
    unsigned short* y  = (unsigned short*)p; p += (size_t)N * 64 * 2;  // tile-major
    unsigned short* f1 = (unsigned short*)p; p += (size_t)N * 64 * 2;
    unsigned short* f2 = (unsigned short*)p; p += (size_t)N * 32 * 2;
    unsigned short* f3 = (unsigned short*)p; p += (size_t)N * 16 * 2;
    int*   cntRB   = (int*)p;               p += (size_t)NBB * 4;
    int*   segoff  = (int*)p;               p += (size_t)NBB * 4;
    int*   segoffT = (int*)p;               p += (size_t)NBB * 4;
    int*   bsum    = (int*)p;

    const size_t QS = (size_t)N * 16;   // tile stride in y

    detect_dtype<<<1, 256, 0, stream>>>(feat, flag);

    // CSR build (also produces cnt, rowptr, dinv) — no global atomics
    parta_hist<<<B, 256, 0, stream>>>(col, cntRB, E, B, NB);
    const int nb = DIVUP(NBB, 1024);
    scan_block_sums<<<nb, 256, 0, stream>>>(cntRB, bsum, NBB);
    scan_bsum<<<1, 256, 0, stream>>>(bsum, nb);
    scan_final<<<nb, 256, 0, stream>>>(cntRB, bsum, segoff, NBB);
    {
        dim3 g(DIVUP(B, 32), DIVUP(NB, 32));
        transpose_seg<<<g, 256, 0, stream>>>(segoff, segoffT, NB, B);
    }
    parta_scatter<<<B, 256, 0, stream>>>(row, col, segoffT, part, E, B, NB);
    csr_build<<<NB, 256, 0, stream>>>(part, segoff, rowptr, cnt, dinv, csr, E, B, NB, N);

    // layer 1: 128 -> 64; 4 tile passes, each 3.2MB working set
    gemm_mfma<128, 64, 0><<<DIVUP(N, 64), 256, 0, stream>>>(feat, W1, dinv, y, QS, N, flag);
    for (int t = 0; t < 4; ++t)
        aggregate16<<<DIVUP(N, 16), 256, 0, stream>>>(y + t * QS, csr, rowptr, cnt,
                                                      dinv, b1, f1, N, 64, t * 16, flag);

    // layer 2: 64 -> 32; 2 tile passes
    gemm_mfma<64, 32, 1><<<DIVUP(N, 64), 256, 0, stream>>>(f1, W2, dinv, y, QS, N, flag);
    for (int t = 0; t < 2; ++t)
        aggregate16<<<DIVUP(N, 16), 256, 0, stream>>>(y + t * QS, csr, rowptr, cnt,
                                                      dinv, b2, f2, N, 32, t * 16, flag);

    // layer 3: 32 -> 16; 1 tile pass
    gemm_mfma<32, 16, 1><<<DIVUP(N, 64), 256, 0, stream>>>(f2, W3, dinv, y, QS, N, flag);
    aggregate16<<<DIVUP(N, 16), 256, 0, stream>>>(y, csr, rowptr, cnt,
                                                  dinv, b3, f3, N, 16, 0, flag);

    // dense head
    head_kernel<<<DIVUP(N, 64), 256, 0, stream>>>(f1, f2, f3, Wfc, bfc, d_out, N, flag);
}